// Round 4
// baseline (163.098 us; speedup 1.0000x reference)
//
#include <hip/hip_runtime.h>
#include <math.h>

#define BLOCK 256
#define C_CLS 80
#define G_MAX 256
#define NCELL1 32
#define NCELLS (NCELL1 * NCELL1)

static __device__ inline float frcp(float x) { return __builtin_amdgcn_rcpf(x); }

static __device__ inline int cell_of(float4 ab) {
    const float cx = 0.5f * (ab.x + ab.z);
    const float cy = 0.5f * (ab.y + ab.w);
    int ix = (int)(cx * (1.0f / 32.0f));
    int iy = (int)(cy * (1.0f / 32.0f));
    ix = ix < 0 ? 0 : (ix > NCELL1 - 1 ? NCELL1 - 1 : ix);
    iy = iy < 0 ? 0 : (iy > NCELL1 - 1 ? NCELL1 - 1 : iy);
    return iy * NCELL1 + ix;
}

// ws layout (4B units): [0..3] float sums {affl, npos, giou, bce}; [8..) hist[NCELLS];
// then curs[NCELLS]; then perm[A]; then minfo[A].

__global__ void k_hist(const float4* __restrict__ anchors, int* __restrict__ hist, int A) {
    const int a = blockIdx.x * blockDim.x + threadIdx.x;
    if (a < A) atomicAdd(&hist[cell_of(anchors[a])], 1);
}

__global__ void k_scan(const int* __restrict__ hist, int* __restrict__ curs) {
    // NCELLS == 1024, launched with 1024 threads
    __shared__ int wsum[16], wincl[16];
    const int t = threadIdx.x, wid = t >> 6, lane = t & 63;
    const int v = hist[t];
    int incl = v;
    #pragma unroll
    for (int off = 1; off < 64; off <<= 1) {
        int n = __shfl_up(incl, off, 64);
        if (lane >= off) incl += n;
    }
    if (lane == 63) wsum[wid] = incl;
    __syncthreads();
    if (t < 16) {
        int si = wsum[t];
        #pragma unroll
        for (int off = 1; off < 16; off <<= 1) {
            int n = __shfl_up(si, off, 64);
            if (t >= off) si += n;
        }
        wincl[t] = si;
    }
    __syncthreads();
    const int prev = wid ? wincl[wid - 1] : 0;
    curs[t] = prev + incl - v;   // exclusive prefix
}

__global__ void k_scatter(const float4* __restrict__ anchors, int* __restrict__ curs,
                          int* __restrict__ perm, int A) {
    const int a = blockIdx.x * blockDim.x + threadIdx.x;
    if (a < A) {
        const int idx = atomicAdd(&curs[cell_of(anchors[a])], 1);
        perm[idx] = a;
    }
}

__global__ __launch_bounds__(BLOCK, 4) void k_match(
    const float4* __restrict__ anchors, const float4* __restrict__ bbox_reg,
    const float* __restrict__ centerness, const float4* __restrict__ gt_boxes,
    const int* __restrict__ gt_labels, const int* __restrict__ perm,
    int* __restrict__ minfo, float* __restrict__ sums, int A, int G)
{
    __shared__ float4 s_cbox[G_MAX];
    __shared__ float  s_car[G_MAX];
    __shared__ int    s_clb[G_MAX];
    __shared__ int    s_wcnt[BLOCK / 64];
    __shared__ float  s_u[BLOCK / 64][4];
    __shared__ int    s_nc;

    const int tid = threadIdx.x;
    const int wid = tid >> 6, lane = tid & 63;
    const int idx = blockIdx.x * BLOCK + tid;
    const bool valid = idx < A;
    const int pa = valid ? perm[idx] : 0;

    float4 ab = make_float4(0.f, 0.f, 0.f, 0.f);
    if (valid) ab = anchors[pa];

    // block union bbox over anchor boxes
    float ux1 = valid ? ab.x : 3.4e38f;
    float uy1 = valid ? ab.y : 3.4e38f;
    float ux2 = valid ? ab.z : -3.4e38f;
    float uy2 = valid ? ab.w : -3.4e38f;
    #pragma unroll
    for (int off = 32; off; off >>= 1) {
        ux1 = fminf(ux1, __shfl_xor(ux1, off, 64));
        uy1 = fminf(uy1, __shfl_xor(uy1, off, 64));
        ux2 = fmaxf(ux2, __shfl_xor(ux2, off, 64));
        uy2 = fmaxf(uy2, __shfl_xor(uy2, off, 64));
    }
    if (lane == 0) { s_u[wid][0] = ux1; s_u[wid][1] = uy1; s_u[wid][2] = ux2; s_u[wid][3] = uy2; }
    __syncthreads();
    ux1 = fminf(fminf(s_u[0][0], s_u[1][0]), fminf(s_u[2][0], s_u[3][0]));
    uy1 = fminf(fminf(s_u[0][1], s_u[1][1]), fminf(s_u[2][1], s_u[3][1]));
    ux2 = fmaxf(fmaxf(s_u[0][2], s_u[1][2]), fmaxf(s_u[2][2], s_u[3][2]));
    uy2 = fmaxf(fmaxf(s_u[0][3], s_u[1][3]), fmaxf(s_u[2][3], s_u[3][3]));

    // candidate GT compaction (ascending j preserves first-occurrence argmax)
    bool keep = false;
    float4 g = make_float4(0.f, 0.f, 0.f, 0.f);
    int lb = 0;
    if (tid < G) {
        g = gt_boxes[tid];
        keep = (g.z >= ux1) && (g.x <= ux2) && (g.w >= uy1) && (g.y <= uy2);
        lb = gt_labels[tid];
    }
    const unsigned long long mk = __ballot(keep);
    if (lane == 0) s_wcnt[wid] = __popcll(mk);
    __syncthreads();
    int prefix = 0;
    for (int w = 0; w < wid; ++w) prefix += s_wcnt[w];
    if (keep) {
        const int p = prefix + __popcll(mk & ((1ull << lane) - 1ull));
        s_cbox[p] = g;
        s_car[p] = (g.z - g.x) * (g.w - g.y);
        s_clb[p] = lb;
    }
    if (tid == 0) s_nc = s_wcnt[0] + s_wcnt[1] + s_wcnt[2] + s_wcnt[3];
    __syncthreads();
    const int nc = s_nc;

    // match over candidates
    const float area_a = (ab.z - ab.x) * (ab.w - ab.y);
    float best = -1.0f;
    int cid = 0;
    for (int j = 0; j < nc; ++j) {
        const float4 c = s_cbox[j];
        const float ga = s_car[j];
        const float lx = fmaxf(ab.x, c.x);
        const float ly = fmaxf(ab.y, c.y);
        const float rx = fminf(ab.z, c.z);
        const float ry = fminf(ab.w, c.w);
        const float iw = fmaxf(rx - lx, 0.0f);
        const float ih = fmaxf(ry - ly, 0.0f);
        const float inter = iw * ih;
        const float iou = inter * frcp(area_a + ga - inter);
        if (iou > best) { best = iou; cid = j; }
    }

    float c_pos = 0.f, c_giou = 0.f, c_bce = 0.f;
    if (valid) {
        const bool pos = best > 0.5f;
        int info = -1;
        if (pos) {
            const float4 mb = s_cbox[cid];
            const int mlab = s_clb[cid];
            info = mlab;

            const float w = ab.z - ab.x;
            const float h = ab.w - ab.y;
            const float cx = ab.x + 0.5f * w;
            const float cy = ab.y + 0.5f * h;
            const float4 t = bbox_reg[pa];
            const float pcx = cx + t.x * w;
            const float pcy = cy + t.y * h;
            const float pw = __expf(t.z * w) * w;
            const float ph = __expf(t.w * h) * h;
            const float p0 = pcx - 0.5f * pw;
            const float p1 = pcy - 0.5f * ph;
            const float p2 = pcx + 0.5f * pw;
            const float p3 = pcy + 0.5f * ph;

            const float lx2 = fmaxf(p0, mb.x);
            const float ly2 = fmaxf(p1, mb.y);
            const float rx2 = fminf(p2, mb.z);
            const float ry2 = fminf(p3, mb.w);
            const float iw2 = fmaxf(rx2 - lx2, 0.0f);
            const float ih2 = fmaxf(ry2 - ly2, 0.0f);
            const float inter2 = iw2 * ih2;
            const float area_p = (p2 - p0) * (p3 - p1);
            const float area_m = (mb.z - mb.x) * (mb.w - mb.y);
            const float uni = area_p + area_m - inter2;
            const float iou2 = inter2 * frcp(uni);
            const float elx = fminf(p0, mb.x);
            const float ely = fminf(p1, mb.y);
            const float erx = fmaxf(p2, mb.z);
            const float ery = fmaxf(p3, mb.w);
            const float ew = fmaxf(erx - elx, 0.0f);
            const float eh = fmaxf(ery - ely, 0.0f);
            const float earea = ew * eh;
            const float giou = iou2 - (earea - uni) * frcp(earea);

            const float lr0 = mb.x - ab.x;
            const float lr1 = mb.z - ab.z;
            const float tb0 = mb.y - ab.y;
            const float tb1 = mb.w - ab.w;
            const float lrmax = fmaxf(lr0, lr1);
            const float lrmin = fminf(lr0, lr1);
            const float tbmax = fmaxf(tb0, tb1);
            const float tbmin = fminf(tb0, tb1);
            const float r_lr = fmaxf(lrmin * frcp(lrmax == 0.0f ? 1.0f : lrmax), 0.0f);
            const float r_tb = fmaxf(tbmin * frcp(tbmax == 0.0f ? 1.0f : tbmax), 0.0f);
            const float ctr_t = sqrtf(fmaxf(r_lr * r_tb, 1e-12f));
            const float c = centerness[pa];
            const float bce = fmaxf(c, 0.0f) + log1pf(__expf(-fabsf(c))) - c * ctr_t;

            c_pos = 1.0f;
            c_giou = giou;
            c_bce = bce;
        }
        minfo[pa] = info;
    }

    // block reduce npos, giou, bce
    __shared__ float red[3][BLOCK / 64];
    float vals[3] = { c_pos, c_giou, c_bce };
    #pragma unroll
    for (int i = 0; i < 3; ++i) {
        float v = vals[i];
        #pragma unroll
        for (int off = 32; off > 0; off >>= 1) v += __shfl_down(v, off, 64);
        if (lane == 0) red[i][wid] = v;
    }
    __syncthreads();
    if (tid < 3) {
        float v = 0.f;
        #pragma unroll
        for (int w = 0; w < BLOCK / 64; ++w) v += red[tid][w];
        atomicAdd(&sums[tid + 1], v);
    }
}

__global__ __launch_bounds__(BLOCK, 4) void k_focal(
    const float* __restrict__ cls_logits, const int* __restrict__ minfo,
    float* __restrict__ sums, int A)
{
    const int a = blockIdx.x * BLOCK + threadIdx.x;
    float c_affl = 0.f;
    if (a < A) {
        const int ct = minfo[a];
        const float4* row4 = reinterpret_cast<const float4*>(cls_logits + (size_t)a * C_CLS);
        float m = -3.4e38f, s = 0.0f, v79 = 0.0f;
        #pragma unroll
        for (int k = 0; k < C_CLS / 4; ++k) {
            const float4 v = row4[k];
            const float m4 = fmaxf(fmaxf(v.x, v.y), fmaxf(v.z, v.w));
            const float mn = fmaxf(m, m4);
            s = s * __expf(m - mn)
              + __expf(v.x - mn) + __expf(v.y - mn)
              + __expf(v.z - mn) + __expf(v.w - mn);
            m = mn;
            if (k == C_CLS / 4 - 1) v79 = v.w;
        }
        const float lse = m + __logf(s);
        const float l_idx = (ct >= 0) ? cls_logits[(size_t)a * C_CLS + ct] : v79;
        const float ce = lse - l_idx;
        const float p = __expf(-ce);
        const float om = 1.0f - p;
        const float fl = om * om * ce;
        const float af = (ct == 1) ? 0.25f : 0.75f;
        c_affl = af * fl;
    }
    __shared__ float red[BLOCK / 64];
    float v = c_affl;
    #pragma unroll
    for (int off = 32; off > 0; off >>= 1) v += __shfl_down(v, off, 64);
    if ((threadIdx.x & 63) == 0) red[threadIdx.x >> 6] = v;
    __syncthreads();
    if (threadIdx.x == 0) {
        float t = 0.f;
        #pragma unroll
        for (int w = 0; w < BLOCK / 64; ++w) t += red[w];
        atomicAdd(&sums[0], t);
    }
}

// ---------------- fallback (round-1 monolithic kernel) ----------------
__global__ __launch_bounds__(BLOCK) void detloss_fallback(
    const float* __restrict__ anchors, const float* __restrict__ cls_logits,
    const float* __restrict__ bbox_reg, const float* __restrict__ centerness,
    const float* __restrict__ gt_boxes, const int* __restrict__ gt_labels,
    float* __restrict__ sums, int A, int G)
{
    __shared__ float4 s_gt[G_MAX];
    __shared__ float  s_ga[G_MAX];
    __shared__ int    s_gl[G_MAX];
    const int tid = threadIdx.x;
    for (int j = tid; j < G; j += BLOCK) {
        float4 g = reinterpret_cast<const float4*>(gt_boxes)[j];
        s_gt[j] = g;
        s_ga[j] = (g.z - g.x) * (g.w - g.y);
        s_gl[j] = gt_labels[j];
    }
    __syncthreads();
    const int a = blockIdx.x * BLOCK + tid;
    float c_affl = 0.f, c_pos = 0.f, c_giou = 0.f, c_bce = 0.f;
    if (a < A) {
        const float4 ab = reinterpret_cast<const float4*>(anchors)[a];
        const float area_a = (ab.z - ab.x) * (ab.w - ab.y);
        float best = -1.0f; int bidx = 0;
        for (int j = 0; j < G; ++j) {
            const float4 g = s_gt[j];
            const float lx = fmaxf(ab.x, g.x), ly = fmaxf(ab.y, g.y);
            const float rx = fminf(ab.z, g.z), ry = fminf(ab.w, g.w);
            const float iw = fmaxf(rx - lx, 0.0f), ih = fmaxf(ry - ly, 0.0f);
            const float inter = iw * ih;
            const float iou = inter * frcp(area_a + s_ga[j] - inter);
            if (iou > best) { best = iou; bidx = j; }
        }
        const bool pos = best > 0.5f;
        const float posf = pos ? 1.0f : 0.0f;
        const float4 mb = s_gt[bidx];
        const int mlab = s_gl[bidx];
        const float4* row4 = reinterpret_cast<const float4*>(cls_logits + (size_t)a * C_CLS);
        float m = -3.4e38f, s = 0.0f, v79 = 0.0f;
        #pragma unroll
        for (int k = 0; k < C_CLS / 4; ++k) {
            const float4 v = row4[k];
            const float m4 = fmaxf(fmaxf(v.x, v.y), fmaxf(v.z, v.w));
            const float mn = fmaxf(m, m4);
            s = s * __expf(m - mn) + __expf(v.x - mn) + __expf(v.y - mn)
              + __expf(v.z - mn) + __expf(v.w - mn);
            m = mn;
            if (k == C_CLS / 4 - 1) v79 = v.w;
        }
        const float lse = m + __logf(s);
        const float l_idx = pos ? cls_logits[(size_t)a * C_CLS + mlab] : v79;
        const float ce = lse - l_idx;
        const float p = __expf(-ce);
        const float om = 1.0f - p;
        const float fl = om * om * ce;
        const float af = (pos && mlab == 1) ? 0.25f : 0.75f;
        c_affl = af * fl;
        const float w = ab.z - ab.x, h = ab.w - ab.y;
        const float cx = ab.x + 0.5f * w, cy = ab.y + 0.5f * h;
        const float4 t = reinterpret_cast<const float4*>(bbox_reg)[a];
        const float pcx = cx + t.x * w, pcy = cy + t.y * h;
        const float pw = __expf(t.z * w) * w, ph = __expf(t.w * h) * h;
        const float p0 = pcx - 0.5f * pw, p1 = pcy - 0.5f * ph;
        const float p2 = pcx + 0.5f * pw, p3 = pcy + 0.5f * ph;
        const float lx2 = fmaxf(p0, mb.x), ly2 = fmaxf(p1, mb.y);
        const float rx2 = fminf(p2, mb.z), ry2 = fminf(p3, mb.w);
        const float iw2 = fmaxf(rx2 - lx2, 0.0f), ih2 = fmaxf(ry2 - ly2, 0.0f);
        const float inter2 = iw2 * ih2;
        const float area_p = (p2 - p0) * (p3 - p1);
        const float area_m = (mb.z - mb.x) * (mb.w - mb.y);
        const float uni = area_p + area_m - inter2;
        const float iou2 = inter2 * frcp(uni);
        const float elx = fminf(p0, mb.x), ely = fminf(p1, mb.y);
        const float erx = fmaxf(p2, mb.z), ery = fmaxf(p3, mb.w);
        const float ew = fmaxf(erx - elx, 0.0f), eh = fmaxf(ery - ely, 0.0f);
        const float earea = ew * eh;
        const float giou = iou2 - (earea - uni) * frcp(earea);
        c_giou = posf * giou;
        const float lr0 = mb.x - ab.x, lr1 = mb.z - ab.z;
        const float tb0 = mb.y - ab.y, tb1 = mb.w - ab.w;
        const float lrmax = fmaxf(lr0, lr1), lrmin = fminf(lr0, lr1);
        const float tbmax = fmaxf(tb0, tb1), tbmin = fminf(tb0, tb1);
        const float r_lr = fmaxf(lrmin * frcp(lrmax == 0.0f ? 1.0f : lrmax), 0.0f);
        const float r_tb = fmaxf(tbmin * frcp(tbmax == 0.0f ? 1.0f : tbmax), 0.0f);
        const float ctr_t = sqrtf(fmaxf(r_lr * r_tb, 1e-12f));
        const float c = centerness[a];
        const float bce = fmaxf(c, 0.0f) + log1pf(__expf(-fabsf(c))) - c * ctr_t;
        c_bce = posf * bce;
        c_pos = posf;
    }
    __shared__ float red[4][BLOCK / 64];
    float vals[4] = { c_affl, c_pos, c_giou, c_bce };
    #pragma unroll
    for (int i = 0; i < 4; ++i) {
        float v = vals[i];
        #pragma unroll
        for (int off = 32; off > 0; off >>= 1) v += __shfl_down(v, off, 64);
        if ((tid & 63) == 0) red[i][tid >> 6] = v;
    }
    __syncthreads();
    if (tid < 4) {
        float v = 0.f;
        #pragma unroll
        for (int w = 0; w < BLOCK / 64; ++w) v += red[tid][w];
        atomicAdd(&sums[tid], v);
    }
}

__global__ void detloss_final(const float* __restrict__ sums,
                              float* __restrict__ out, int A)
{
    const float s_affl = sums[0];
    const float npos   = sums[1];
    const float sgiou  = sums[2];
    const float sbce   = sums[3];
    float cls = s_affl / (float)A;
    const float denom = fmaxf(npos, 1.0f);
    float reg = 1.0f - sgiou / denom;
    float ctr = sbce / denom;
    const float has = (npos > 0.0f) ? 1.0f : 0.0f;
    cls *= has; reg *= has; ctr *= has;
    out[0] = cls + reg + ctr;
    out[1] = cls;
    out[2] = reg;
    out[3] = ctr;
}

extern "C" void kernel_launch(void* const* d_in, const int* in_sizes, int n_in,
                              void* d_out, int out_size, void* d_ws, size_t ws_size,
                              hipStream_t stream) {
    const float* anchors    = (const float*)d_in[0];
    const float* cls_logits = (const float*)d_in[1];
    const float* bbox_reg   = (const float*)d_in[2];
    const float* centerness = (const float*)d_in[3];
    const float* gt_boxes   = (const float*)d_in[4];
    const int*   gt_labels  = (const int*)d_in[5];
    const int A = in_sizes[0] / 4;
    int G = in_sizes[4] / 4;
    if (G > G_MAX) G = G_MAX;

    float* sums = (float*)d_ws;
    const int grid = (A + BLOCK - 1) / BLOCK;

    const size_t need = (size_t)(8 + 2 * NCELLS + 2 * (size_t)A) * 4;
    if (ws_size >= need) {
        int* iw   = (int*)d_ws;
        int* hist = iw + 8;
        int* curs = iw + 8 + NCELLS;
        int* perm = iw + 8 + 2 * NCELLS;
        int* minfo = perm + A;

        hipMemsetAsync(d_ws, 0, (8 + NCELLS) * sizeof(int), stream);
        k_hist<<<grid, BLOCK, 0, stream>>>((const float4*)anchors, hist, A);
        k_scan<<<1, NCELLS, 0, stream>>>(hist, curs);
        k_scatter<<<grid, BLOCK, 0, stream>>>((const float4*)anchors, curs, perm, A);
        k_match<<<grid, BLOCK, 0, stream>>>((const float4*)anchors, (const float4*)bbox_reg,
                                            centerness, (const float4*)gt_boxes, gt_labels,
                                            perm, minfo, sums, A, G);
        k_focal<<<grid, BLOCK, 0, stream>>>(cls_logits, minfo, sums, A);
    } else {
        hipMemsetAsync(d_ws, 0, 4 * sizeof(float), stream);
        detloss_fallback<<<grid, BLOCK, 0, stream>>>(anchors, cls_logits, bbox_reg,
                                                     centerness, gt_boxes, gt_labels,
                                                     sums, A, G);
    }
    detloss_final<<<1, 1, 0, stream>>>(sums, (float*)d_out, A);
}

// Round 5
// 61.091 us; speedup vs baseline: 2.6698x; 2.6698x over previous
//
#include <hip/hip_runtime.h>
#include <math.h>

#define BLOCK 256
#define C_CLS 80
#define G_MAX 256
#define NCELL1 32
#define NCELLS (NCELL1 * NCELL1)
#define CAP 96

static __device__ inline float frcp(float x) { return __builtin_amdgcn_rcpf(x); }

static __device__ inline int cell_of(float4 ab) {
    const float cx = 0.5f * (ab.x + ab.z);
    const float cy = 0.5f * (ab.y + ab.w);
    int ix = (int)(cx * (1.0f / 32.0f));
    int iy = (int)(cy * (1.0f / 32.0f));
    ix = ix < 0 ? 0 : (ix > NCELL1 - 1 ? NCELL1 - 1 : ix);
    iy = iy < 0 ? 0 : (iy > NCELL1 - 1 ? NCELL1 - 1 : iy);
    return iy * NCELL1 + ix;
}

// ws layout (floats): [0..3] sums; [4..7] pad; [8..8+1024) cnts (int);
// boxes float4[NCELLS*CAP] at float-offset 1032; labs int[NCELLS*CAP] after.

__global__ __launch_bounds__(256) void k_build(
    const float4* __restrict__ gt, const int* __restrict__ gl,
    int* __restrict__ cnts, float4* __restrict__ boxes, int* __restrict__ labs,
    int G)
{
    __shared__ int s_wcnt[4];
    const int cell = blockIdx.x;
    const int ix = cell & (NCELL1 - 1), iy = cell >> 5;
    const float Dx1 = 32.0f * ix - 64.0f, Dx2 = 32.0f * ix + 96.0f;
    const float Dy1 = 32.0f * iy - 64.0f, Dy2 = 32.0f * iy + 96.0f;

    const int tid = threadIdx.x, wid = tid >> 6, lane = tid & 63;
    bool keep = false;
    float4 g = make_float4(0.f, 0.f, 0.f, 0.f);
    int lb = 0;
    if (tid < G) {
        g = gt[tid];
        keep = (g.x <= Dx2) && (g.z >= Dx1) && (g.y <= Dy2) && (g.w >= Dy1);
        lb = gl[tid];
    }
    const unsigned long long mk = __ballot(keep);
    if (lane == 0) s_wcnt[wid] = __popcll(mk);
    __syncthreads();
    int prefix = 0;
    for (int w = 0; w < wid; ++w) prefix += s_wcnt[w];
    if (keep) {
        const int p = prefix + __popcll(mk & ((1ull << lane) - 1ull));
        if (p < CAP) {
            boxes[(size_t)cell * CAP + p] = g;
            labs[(size_t)cell * CAP + p] = lb;
        }
    }
    if (tid == 0) {
        const int tot = s_wcnt[0] + s_wcnt[1] + s_wcnt[2] + s_wcnt[3];
        cnts[cell] = (tot > CAP) ? (1 << 30) : tot;
    }
}

__global__ __launch_bounds__(BLOCK) void k_main(
    const float* __restrict__ anchors, const float* __restrict__ cls_logits,
    const float* __restrict__ bbox_reg, const float* __restrict__ centerness,
    const float* __restrict__ gt_boxes, const int* __restrict__ gt_labels,
    const int* __restrict__ cnts, const float4* __restrict__ boxes,
    const int* __restrict__ labs,
    float* __restrict__ sums, int A, int G)
{
    const int tid = threadIdx.x;
    const int a = blockIdx.x * BLOCK + tid;
    const bool valid = a < A;

    float4 ab = make_float4(0.f, 0.f, 0.f, 0.f);
    if (valid) ab = reinterpret_cast<const float4*>(anchors)[a];
    const float area_a = (ab.z - ab.x) * (ab.w - ab.y);

    const int cell = cell_of(ab);
    const int cnt = valid ? cnts[cell] : 0;
    const bool big = cnt > CAP;
    const int c2 = big ? 0 : cnt;

    int wmax = c2;
    #pragma unroll
    for (int off = 1; off < 64; off <<= 1)
        wmax = max(wmax, __shfl_xor(wmax, off, 64));

    const float4* __restrict__ bl = boxes + (size_t)cell * CAP;
    float best = -1.0f;
    int bestk = 0, bidx = 0;
    float4 bb = make_float4(0.f, 0.f, 0.f, 0.f);

    for (int j = 0; j < wmax; ++j) {
        const float4 g = bl[j];
        const float ga = (g.z - g.x) * (g.w - g.y);
        const float lx = fmaxf(ab.x, g.x);
        const float ly = fmaxf(ab.y, g.y);
        const float rx = fminf(ab.z, g.z);
        const float ry = fminf(ab.w, g.w);
        const float iw = fmaxf(rx - lx, 0.0f);
        const float ih = fmaxf(ry - ly, 0.0f);
        const float inter = iw * ih;
        const float iou = inter * frcp(area_a + ga - inter);
        if ((j < c2) && (iou > best)) { best = iou; bestk = j; bb = g; }
    }

    // near-never taken: candidate list overflowed -> exact full loop
    if (__ballot(big) != 0ull) {
        if (big) {
            best = -1.0f; bidx = 0;
            for (int j = 0; j < G; ++j) {
                const float4 g = reinterpret_cast<const float4*>(gt_boxes)[j];
                const float ga = (g.z - g.x) * (g.w - g.y);
                const float lx = fmaxf(ab.x, g.x);
                const float ly = fmaxf(ab.y, g.y);
                const float rx = fminf(ab.z, g.z);
                const float ry = fminf(ab.w, g.w);
                const float iw = fmaxf(rx - lx, 0.0f);
                const float ih = fmaxf(ry - ly, 0.0f);
                const float inter = iw * ih;
                const float iou = inter * frcp(area_a + ga - inter);
                if (iou > best) { best = iou; bidx = j; bb = g; }
            }
        }
    }

    float c_affl = 0.f, c_pos = 0.f, c_giou = 0.f, c_bce = 0.f;

    if (valid) {
        const bool pos = best > 0.5f;
        int lab = -1;
        if (pos) lab = big ? gt_labels[bidx] : labs[(size_t)cell * CAP + bestk];
        const float4 mb = bb;

        // ---- focal loss: online logsumexp over the 80-class row ----
        const float4* row4 = reinterpret_cast<const float4*>(cls_logits + (size_t)a * C_CLS);
        float m = -3.4e38f, s = 0.0f, v79 = 0.0f;
        #pragma unroll
        for (int k = 0; k < C_CLS / 4; ++k) {
            const float4 v = row4[k];
            const float m4 = fmaxf(fmaxf(v.x, v.y), fmaxf(v.z, v.w));
            const float mn = fmaxf(m, m4);
            s = s * __expf(m - mn)
              + __expf(v.x - mn) + __expf(v.y - mn)
              + __expf(v.z - mn) + __expf(v.w - mn);
            m = mn;
            if (k == C_CLS / 4 - 1) v79 = v.w;
        }
        const float lse = m + __logf(s);
        const float l_idx = pos ? cls_logits[(size_t)a * C_CLS + lab] : v79;
        const float ce = lse - l_idx;
        const float p  = __expf(-ce);
        const float om = 1.0f - p;
        const float fl = om * om * ce;
        const float af = (pos && lab == 1) ? 0.25f : 0.75f;
        c_affl = af * fl;

        if (pos) {
            // ---- decode ----
            const float w  = ab.z - ab.x;
            const float h  = ab.w - ab.y;
            const float cx = ab.x + 0.5f * w;
            const float cy = ab.y + 0.5f * h;
            const float4 t = reinterpret_cast<const float4*>(bbox_reg)[a];
            const float pcx = cx + t.x * w;
            const float pcy = cy + t.y * h;
            const float pw  = __expf(t.z * w) * w;
            const float ph  = __expf(t.w * h) * h;
            const float p0 = pcx - 0.5f * pw;
            const float p1 = pcy - 0.5f * ph;
            const float p2 = pcx + 0.5f * pw;
            const float p3 = pcy + 0.5f * ph;

            // ---- paired GIoU ----
            const float lx2 = fmaxf(p0, mb.x);
            const float ly2 = fmaxf(p1, mb.y);
            const float rx2 = fminf(p2, mb.z);
            const float ry2 = fminf(p3, mb.w);
            const float iw2 = fmaxf(rx2 - lx2, 0.0f);
            const float ih2 = fmaxf(ry2 - ly2, 0.0f);
            const float inter2 = iw2 * ih2;
            const float area_p = (p2 - p0) * (p3 - p1);
            const float area_m = (mb.z - mb.x) * (mb.w - mb.y);
            const float uni = area_p + area_m - inter2;
            const float iou2 = inter2 * frcp(uni);
            const float elx = fminf(p0, mb.x);
            const float ely = fminf(p1, mb.y);
            const float erx = fmaxf(p2, mb.z);
            const float ery = fmaxf(p3, mb.w);
            const float ew = fmaxf(erx - elx, 0.0f);
            const float eh = fmaxf(ery - ely, 0.0f);
            const float earea = ew * eh;
            const float giou = iou2 - (earea - uni) * frcp(earea);
            c_giou = giou;

            // ---- centerness ----
            const float lr0 = mb.x - ab.x;
            const float lr1 = mb.z - ab.z;
            const float tb0 = mb.y - ab.y;
            const float tb1 = mb.w - ab.w;
            const float lrmax = fmaxf(lr0, lr1);
            const float lrmin = fminf(lr0, lr1);
            const float tbmax = fmaxf(tb0, tb1);
            const float tbmin = fminf(tb0, tb1);
            const float r_lr = fmaxf(lrmin * frcp(lrmax == 0.0f ? 1.0f : lrmax), 0.0f);
            const float r_tb = fmaxf(tbmin * frcp(tbmax == 0.0f ? 1.0f : tbmax), 0.0f);
            const float ctr_t = sqrtf(fmaxf(r_lr * r_tb, 1e-12f));
            const float c = centerness[a];
            const float bce = fmaxf(c, 0.0f) + log1pf(__expf(-fabsf(c))) - c * ctr_t;
            c_bce = bce;
            c_pos = 1.0f;
        }
    }

    __shared__ float red[4][BLOCK / 64];
    float vals[4] = { c_affl, c_pos, c_giou, c_bce };
    #pragma unroll
    for (int i = 0; i < 4; ++i) {
        float v = vals[i];
        #pragma unroll
        for (int off = 32; off > 0; off >>= 1) v += __shfl_down(v, off, 64);
        if ((tid & 63) == 0) red[i][tid >> 6] = v;
    }
    __syncthreads();
    if (tid < 4) {
        float v = 0.f;
        #pragma unroll
        for (int wv = 0; wv < BLOCK / 64; ++wv) v += red[tid][wv];
        atomicAdd(&sums[tid], v);
    }
}

// ---------------- fallback (round-1 monolithic kernel) ----------------
__global__ __launch_bounds__(BLOCK) void detloss_fallback(
    const float* __restrict__ anchors, const float* __restrict__ cls_logits,
    const float* __restrict__ bbox_reg, const float* __restrict__ centerness,
    const float* __restrict__ gt_boxes, const int* __restrict__ gt_labels,
    float* __restrict__ sums, int A, int G)
{
    __shared__ float4 s_gt[G_MAX];
    __shared__ float  s_ga[G_MAX];
    __shared__ int    s_gl[G_MAX];
    const int tid = threadIdx.x;
    for (int j = tid; j < G; j += BLOCK) {
        float4 g = reinterpret_cast<const float4*>(gt_boxes)[j];
        s_gt[j] = g;
        s_ga[j] = (g.z - g.x) * (g.w - g.y);
        s_gl[j] = gt_labels[j];
    }
    __syncthreads();
    const int a = blockIdx.x * BLOCK + tid;
    float c_affl = 0.f, c_pos = 0.f, c_giou = 0.f, c_bce = 0.f;
    if (a < A) {
        const float4 ab = reinterpret_cast<const float4*>(anchors)[a];
        const float area_a = (ab.z - ab.x) * (ab.w - ab.y);
        float best = -1.0f; int bidx = 0;
        for (int j = 0; j < G; ++j) {
            const float4 g = s_gt[j];
            const float lx = fmaxf(ab.x, g.x), ly = fmaxf(ab.y, g.y);
            const float rx = fminf(ab.z, g.z), ry = fminf(ab.w, g.w);
            const float iw = fmaxf(rx - lx, 0.0f), ih = fmaxf(ry - ly, 0.0f);
            const float inter = iw * ih;
            const float iou = inter * frcp(area_a + s_ga[j] - inter);
            if (iou > best) { best = iou; bidx = j; }
        }
        const bool pos = best > 0.5f;
        const float posf = pos ? 1.0f : 0.0f;
        const float4 mb = s_gt[bidx];
        const int mlab = s_gl[bidx];
        const float4* row4 = reinterpret_cast<const float4*>(cls_logits + (size_t)a * C_CLS);
        float m = -3.4e38f, s = 0.0f, v79 = 0.0f;
        #pragma unroll
        for (int k = 0; k < C_CLS / 4; ++k) {
            const float4 v = row4[k];
            const float m4 = fmaxf(fmaxf(v.x, v.y), fmaxf(v.z, v.w));
            const float mn = fmaxf(m, m4);
            s = s * __expf(m - mn) + __expf(v.x - mn) + __expf(v.y - mn)
              + __expf(v.z - mn) + __expf(v.w - mn);
            m = mn;
            if (k == C_CLS / 4 - 1) v79 = v.w;
        }
        const float lse = m + __logf(s);
        const float l_idx = pos ? cls_logits[(size_t)a * C_CLS + mlab] : v79;
        const float ce = lse - l_idx;
        const float p = __expf(-ce);
        const float om = 1.0f - p;
        const float fl = om * om * ce;
        const float af = (pos && mlab == 1) ? 0.25f : 0.75f;
        c_affl = af * fl;
        const float w = ab.z - ab.x, h = ab.w - ab.y;
        const float cx = ab.x + 0.5f * w, cy = ab.y + 0.5f * h;
        const float4 t = reinterpret_cast<const float4*>(bbox_reg)[a];
        const float pcx = cx + t.x * w, pcy = cy + t.y * h;
        const float pw = __expf(t.z * w) * w, ph = __expf(t.w * h) * h;
        const float p0 = pcx - 0.5f * pw, p1 = pcy - 0.5f * ph;
        const float p2 = pcx + 0.5f * pw, p3 = pcy + 0.5f * ph;
        const float lx2 = fmaxf(p0, mb.x), ly2 = fmaxf(p1, mb.y);
        const float rx2 = fminf(p2, mb.z), ry2 = fminf(p3, mb.w);
        const float iw2 = fmaxf(rx2 - lx2, 0.0f), ih2 = fmaxf(ry2 - ly2, 0.0f);
        const float inter2 = iw2 * ih2;
        const float area_p = (p2 - p0) * (p3 - p1);
        const float area_m = (mb.z - mb.x) * (mb.w - mb.y);
        const float uni = area_p + area_m - inter2;
        const float iou2 = inter2 * frcp(uni);
        const float elx = fminf(p0, mb.x), ely = fminf(p1, mb.y);
        const float erx = fmaxf(p2, mb.z), ery = fmaxf(p3, mb.w);
        const float ew = fmaxf(erx - elx, 0.0f), eh = fmaxf(ery - ely, 0.0f);
        const float earea = ew * eh;
        const float giou = iou2 - (earea - uni) * frcp(earea);
        c_giou = posf * giou;
        const float lr0 = mb.x - ab.x, lr1 = mb.z - ab.z;
        const float tb0 = mb.y - ab.y, tb1 = mb.w - ab.w;
        const float lrmax = fmaxf(lr0, lr1), lrmin = fminf(lr0, lr1);
        const float tbmax = fmaxf(tb0, tb1), tbmin = fminf(tb0, tb1);
        const float r_lr = fmaxf(lrmin * frcp(lrmax == 0.0f ? 1.0f : lrmax), 0.0f);
        const float r_tb = fmaxf(tbmin * frcp(tbmax == 0.0f ? 1.0f : tbmax), 0.0f);
        const float ctr_t = sqrtf(fmaxf(r_lr * r_tb, 1e-12f));
        const float c = centerness[a];
        const float bce = fmaxf(c, 0.0f) + log1pf(__expf(-fabsf(c))) - c * ctr_t;
        c_bce = posf * bce;
        c_pos = posf;
    }
    __shared__ float red[4][BLOCK / 64];
    float vals[4] = { c_affl, c_pos, c_giou, c_bce };
    #pragma unroll
    for (int i = 0; i < 4; ++i) {
        float v = vals[i];
        #pragma unroll
        for (int off = 32; off > 0; off >>= 1) v += __shfl_down(v, off, 64);
        if ((tid & 63) == 0) red[i][tid >> 6] = v;
    }
    __syncthreads();
    if (tid < 4) {
        float v = 0.f;
        #pragma unroll
        for (int w = 0; w < BLOCK / 64; ++w) v += red[tid][w];
        atomicAdd(&sums[tid], v);
    }
}

__global__ void detloss_final(const float* __restrict__ sums,
                              float* __restrict__ out, int A)
{
    const float s_affl = sums[0];
    const float npos   = sums[1];
    const float sgiou  = sums[2];
    const float sbce   = sums[3];
    float cls = s_affl / (float)A;
    const float denom = fmaxf(npos, 1.0f);
    float reg = 1.0f - sgiou / denom;
    float ctr = sbce / denom;
    const float has = (npos > 0.0f) ? 1.0f : 0.0f;
    cls *= has; reg *= has; ctr *= has;
    out[0] = cls + reg + ctr;
    out[1] = cls;
    out[2] = reg;
    out[3] = ctr;
}

extern "C" void kernel_launch(void* const* d_in, const int* in_sizes, int n_in,
                              void* d_out, int out_size, void* d_ws, size_t ws_size,
                              hipStream_t stream) {
    const float* anchors    = (const float*)d_in[0];
    const float* cls_logits = (const float*)d_in[1];
    const float* bbox_reg   = (const float*)d_in[2];
    const float* centerness = (const float*)d_in[3];
    const float* gt_boxes   = (const float*)d_in[4];
    const int*   gt_labels  = (const int*)d_in[5];
    const int A = in_sizes[0] / 4;
    const int G = in_sizes[4] / 4;

    float* sums = (float*)d_ws;
    const int grid = (A + BLOCK - 1) / BLOCK;

    // ws: 8 floats + 1024 cnts + CAP*NCELLS float4 boxes + CAP*NCELLS labs
    const size_t need = (size_t)(8 + NCELLS + (size_t)NCELLS * CAP * 4
                                 + (size_t)NCELLS * CAP) * 4;
    hipMemsetAsync(sums, 0, 4 * sizeof(float), stream);

    if (ws_size >= need && G <= 256) {
        int*    cnts  = (int*)d_ws + 8;
        float4* boxes = (float4*)((float*)d_ws + 8 + NCELLS);
        int*    labs  = (int*)((float*)d_ws + 8 + NCELLS + (size_t)NCELLS * CAP * 4);

        k_build<<<NCELLS, 256, 0, stream>>>((const float4*)gt_boxes, gt_labels,
                                            cnts, boxes, labs, G);
        k_main<<<grid, BLOCK, 0, stream>>>(anchors, cls_logits, bbox_reg,
                                           centerness, gt_boxes, gt_labels,
                                           cnts, boxes, labs, sums, A, G);
    } else {
        const int Gc = G > G_MAX ? G_MAX : G;
        detloss_fallback<<<grid, BLOCK, 0, stream>>>(anchors, cls_logits, bbox_reg,
                                                     centerness, gt_boxes, gt_labels,
                                                     sums, A, Gc);
    }
    detloss_final<<<1, 1, 0, stream>>>(sums, (float*)d_out, A);
}

// Round 6
// 46.463 us; speedup vs baseline: 3.5103x; 1.3148x over previous
//
#include <hip/hip_runtime.h>
#include <math.h>

#define BLOCK 256
#define C_CLS 80
#define G_MAX 256
#define NCELL1 32
#define NCELLS (NCELL1 * NCELL1)
#define CAP 96
#define CHUNK 8

static __device__ inline float frcp(float x) { return __builtin_amdgcn_rcpf(x); }

static __device__ inline int cell_of(float4 ab) {
    const float cx = 0.5f * (ab.x + ab.z);
    const float cy = 0.5f * (ab.y + ab.w);
    int ix = (int)(cx * (1.0f / 32.0f));
    int iy = (int)(cy * (1.0f / 32.0f));
    ix = ix < 0 ? 0 : (ix > NCELL1 - 1 ? NCELL1 - 1 : ix);
    iy = iy < 0 ? 0 : (iy > NCELL1 - 1 ? NCELL1 - 1 : iy);
    return iy * NCELL1 + ix;
}

// ws layout (floats): [0..3] sums; [4..7] pad; [8..8+1024) cnts (int);
// boxes float4[NCELLS*CAP]; labs int[NCELLS*CAP].

__global__ __launch_bounds__(256) void k_build(
    const float4* __restrict__ gt, const int* __restrict__ gl,
    int* __restrict__ cnts, float4* __restrict__ boxes, int* __restrict__ labs,
    int G)
{
    __shared__ int s_wcnt[4];
    const int cell = blockIdx.x;
    const int ix = cell & (NCELL1 - 1), iy = cell >> 5;
    const float Dx1 = 32.0f * ix - 64.0f, Dx2 = 32.0f * ix + 96.0f;
    const float Dy1 = 32.0f * iy - 64.0f, Dy2 = 32.0f * iy + 96.0f;

    const int tid = threadIdx.x, wid = tid >> 6, lane = tid & 63;
    bool keep = false;
    float4 g = make_float4(0.f, 0.f, 0.f, 0.f);
    int lb = 0;
    if (tid < G) {
        g = gt[tid];
        keep = (g.x <= Dx2) && (g.z >= Dx1) && (g.y <= Dy2) && (g.w >= Dy1);
        lb = gl[tid];
    }
    const unsigned long long mk = __ballot(keep);
    if (lane == 0) s_wcnt[wid] = __popcll(mk);
    __syncthreads();
    int prefix = 0;
    for (int w = 0; w < wid; ++w) prefix += s_wcnt[w];
    if (keep) {
        const int p = prefix + __popcll(mk & ((1ull << lane) - 1ull));
        if (p < CAP) {
            boxes[(size_t)cell * CAP + p] = g;
            labs[(size_t)cell * CAP + p] = lb;
        }
    }
    const int tot = s_wcnt[0] + s_wcnt[1] + s_wcnt[2] + s_wcnt[3];
    if (tot <= CAP) {
        // sentinel pad: IoU with any real anchor is exactly 0
        const float4 sent = make_float4(1e30f, 1e30f, 1e30f, 1e30f);
        for (int p = tot + tid; p < CAP; p += 256) {
            boxes[(size_t)cell * CAP + p] = sent;
            labs[(size_t)cell * CAP + p] = 0;
        }
    }
    if (tid == 0) cnts[cell] = (tot > CAP) ? (1 << 30) : tot;
}

__global__ __launch_bounds__(BLOCK) void k_main(
    const float* __restrict__ anchors, const float* __restrict__ cls_logits,
    const float* __restrict__ bbox_reg, const float* __restrict__ centerness,
    const float* __restrict__ gt_boxes, const int* __restrict__ gt_labels,
    const int* __restrict__ cnts, const float4* __restrict__ boxes,
    const int* __restrict__ labs,
    float* __restrict__ sums, int A, int G)
{
    const int tid = threadIdx.x;
    const int a = blockIdx.x * BLOCK + tid;
    const bool valid = a < A;

    float4 ab = make_float4(0.f, 0.f, 0.f, 0.f);
    if (valid) ab = reinterpret_cast<const float4*>(anchors)[a];
    const float area_a = (ab.z - ab.x) * (ab.w - ab.y);

    const int cell = cell_of(ab);
    const int cnt = valid ? cnts[cell] : 0;
    const bool big = cnt > CAP;
    const int c2 = big ? 0 : cnt;

    int wmax = c2;
    #pragma unroll
    for (int off = 1; off < 64; off <<= 1)
        wmax = max(wmax, __shfl_xor(wmax, off, 64));
    const int nch = (wmax + CHUNK - 1) / CHUNK;   // lists sentinel-padded to CAP

    const float4* __restrict__ bl = boxes + (size_t)cell * CAP;
    float best = -1.0f;
    int bestk = 0, bidx = 0;

    for (int ch = 0; ch < nch; ++ch) {
        const int j0 = ch * CHUNK;
        float4 gg[CHUNK];
        #pragma unroll
        for (int u = 0; u < CHUNK; ++u) gg[u] = bl[j0 + u];
        #pragma unroll
        for (int u = 0; u < CHUNK; ++u) {
            const float4 g = gg[u];
            const float ga = (g.z - g.x) * (g.w - g.y);
            const float lx = fmaxf(ab.x, g.x);
            const float ly = fmaxf(ab.y, g.y);
            const float rx = fminf(ab.z, g.z);
            const float ry = fminf(ab.w, g.w);
            const float iw = fmaxf(rx - lx, 0.0f);
            const float ih = fmaxf(ry - ly, 0.0f);
            const float inter = iw * ih;
            const float iou = inter * frcp(area_a + ga - inter);
            if (iou > best) { best = iou; bestk = j0 + u; }
        }
    }

    // near-never taken: candidate list overflowed -> exact full loop
    if (__ballot(big) != 0ull) {
        if (big) {
            best = -1.0f; bidx = 0;
            for (int j = 0; j < G; ++j) {
                const float4 g = reinterpret_cast<const float4*>(gt_boxes)[j];
                const float ga = (g.z - g.x) * (g.w - g.y);
                const float lx = fmaxf(ab.x, g.x);
                const float ly = fmaxf(ab.y, g.y);
                const float rx = fminf(ab.z, g.z);
                const float ry = fminf(ab.w, g.w);
                const float iw = fmaxf(rx - lx, 0.0f);
                const float ih = fmaxf(ry - ly, 0.0f);
                const float inter = iw * ih;
                const float iou = inter * frcp(area_a + ga - inter);
                if (iou > best) { best = iou; bidx = j; }
            }
        }
    }

    float c_affl = 0.f, c_pos = 0.f, c_giou = 0.f, c_bce = 0.f;

    if (valid) {
        const bool pos = best > 0.5f;
        int lab = -1;
        float4 mb = make_float4(0.f, 0.f, 0.f, 0.f);
        if (pos) {
            if (big) { mb = reinterpret_cast<const float4*>(gt_boxes)[bidx]; lab = gt_labels[bidx]; }
            else     { mb = bl[bestk]; lab = labs[(size_t)cell * CAP + bestk]; }
        }

        // ---- focal loss: online logsumexp over the 80-class row ----
        const float4* row4 = reinterpret_cast<const float4*>(cls_logits + (size_t)a * C_CLS);
        float m = -3.4e38f, s = 0.0f, v79 = 0.0f;
        #pragma unroll
        for (int k = 0; k < C_CLS / 4; ++k) {
            const float4 v = row4[k];
            const float m4 = fmaxf(fmaxf(v.x, v.y), fmaxf(v.z, v.w));
            const float mn = fmaxf(m, m4);
            s = s * __expf(m - mn)
              + __expf(v.x - mn) + __expf(v.y - mn)
              + __expf(v.z - mn) + __expf(v.w - mn);
            m = mn;
            if (k == C_CLS / 4 - 1) v79 = v.w;
        }
        const float lse = m + __logf(s);
        const float l_idx = pos ? cls_logits[(size_t)a * C_CLS + lab] : v79;
        const float ce = lse - l_idx;
        const float p  = __expf(-ce);
        const float om = 1.0f - p;
        const float fl = om * om * ce;
        const float af = (pos && lab == 1) ? 0.25f : 0.75f;
        c_affl = af * fl;

        if (pos) {
            // ---- decode ----
            const float w  = ab.z - ab.x;
            const float h  = ab.w - ab.y;
            const float cx = ab.x + 0.5f * w;
            const float cy = ab.y + 0.5f * h;
            const float4 t = reinterpret_cast<const float4*>(bbox_reg)[a];
            const float pcx = cx + t.x * w;
            const float pcy = cy + t.y * h;
            const float pw  = __expf(t.z * w) * w;
            const float ph  = __expf(t.w * h) * h;
            const float p0 = pcx - 0.5f * pw;
            const float p1 = pcy - 0.5f * ph;
            const float p2 = pcx + 0.5f * pw;
            const float p3 = pcy + 0.5f * ph;

            // ---- paired GIoU ----
            const float lx2 = fmaxf(p0, mb.x);
            const float ly2 = fmaxf(p1, mb.y);
            const float rx2 = fminf(p2, mb.z);
            const float ry2 = fminf(p3, mb.w);
            const float iw2 = fmaxf(rx2 - lx2, 0.0f);
            const float ih2 = fmaxf(ry2 - ly2, 0.0f);
            const float inter2 = iw2 * ih2;
            const float area_p = (p2 - p0) * (p3 - p1);
            const float area_m = (mb.z - mb.x) * (mb.w - mb.y);
            const float uni = area_p + area_m - inter2;
            const float iou2 = inter2 * frcp(uni);
            const float elx = fminf(p0, mb.x);
            const float ely = fminf(p1, mb.y);
            const float erx = fmaxf(p2, mb.z);
            const float ery = fmaxf(p3, mb.w);
            const float ew = fmaxf(erx - elx, 0.0f);
            const float eh = fmaxf(ery - ely, 0.0f);
            const float earea = ew * eh;
            const float giou = iou2 - (earea - uni) * frcp(earea);
            c_giou = giou;

            // ---- centerness ----
            const float lr0 = mb.x - ab.x;
            const float lr1 = mb.z - ab.z;
            const float tb0 = mb.y - ab.y;
            const float tb1 = mb.w - ab.w;
            const float lrmax = fmaxf(lr0, lr1);
            const float lrmin = fminf(lr0, lr1);
            const float tbmax = fmaxf(tb0, tb1);
            const float tbmin = fminf(tb0, tb1);
            const float r_lr = fmaxf(lrmin * frcp(lrmax == 0.0f ? 1.0f : lrmax), 0.0f);
            const float r_tb = fmaxf(tbmin * frcp(tbmax == 0.0f ? 1.0f : tbmax), 0.0f);
            const float ctr_t = sqrtf(fmaxf(r_lr * r_tb, 1e-12f));
            const float c = centerness[a];
            const float bce = fmaxf(c, 0.0f) + log1pf(__expf(-fabsf(c))) - c * ctr_t;
            c_bce = bce;
            c_pos = 1.0f;
        }
    }

    __shared__ float red[4][BLOCK / 64];
    float vals[4] = { c_affl, c_pos, c_giou, c_bce };
    #pragma unroll
    for (int i = 0; i < 4; ++i) {
        float v = vals[i];
        #pragma unroll
        for (int off = 32; off > 0; off >>= 1) v += __shfl_down(v, off, 64);
        if ((tid & 63) == 0) red[i][tid >> 6] = v;
    }
    __syncthreads();
    if (tid < 4) {
        float v = 0.f;
        #pragma unroll
        for (int wv = 0; wv < BLOCK / 64; ++wv) v += red[tid][wv];
        atomicAdd(&sums[tid], v);
    }
}

// ---------------- fallback (round-1 monolithic kernel) ----------------
__global__ __launch_bounds__(BLOCK) void detloss_fallback(
    const float* __restrict__ anchors, const float* __restrict__ cls_logits,
    const float* __restrict__ bbox_reg, const float* __restrict__ centerness,
    const float* __restrict__ gt_boxes, const int* __restrict__ gt_labels,
    float* __restrict__ sums, int A, int G)
{
    __shared__ float4 s_gt[G_MAX];
    __shared__ float  s_ga[G_MAX];
    __shared__ int    s_gl[G_MAX];
    const int tid = threadIdx.x;
    for (int j = tid; j < G; j += BLOCK) {
        float4 g = reinterpret_cast<const float4*>(gt_boxes)[j];
        s_gt[j] = g;
        s_ga[j] = (g.z - g.x) * (g.w - g.y);
        s_gl[j] = gt_labels[j];
    }
    __syncthreads();
    const int a = blockIdx.x * BLOCK + tid;
    float c_affl = 0.f, c_pos = 0.f, c_giou = 0.f, c_bce = 0.f;
    if (a < A) {
        const float4 ab = reinterpret_cast<const float4*>(anchors)[a];
        const float area_a = (ab.z - ab.x) * (ab.w - ab.y);
        float best = -1.0f; int bidx = 0;
        for (int j = 0; j < G; ++j) {
            const float4 g = s_gt[j];
            const float lx = fmaxf(ab.x, g.x), ly = fmaxf(ab.y, g.y);
            const float rx = fminf(ab.z, g.z), ry = fminf(ab.w, g.w);
            const float iw = fmaxf(rx - lx, 0.0f), ih = fmaxf(ry - ly, 0.0f);
            const float inter = iw * ih;
            const float iou = inter * frcp(area_a + s_ga[j] - inter);
            if (iou > best) { best = iou; bidx = j; }
        }
        const bool pos = best > 0.5f;
        const float posf = pos ? 1.0f : 0.0f;
        const float4 mb = s_gt[bidx];
        const int mlab = s_gl[bidx];
        const float4* row4 = reinterpret_cast<const float4*>(cls_logits + (size_t)a * C_CLS);
        float m = -3.4e38f, s = 0.0f, v79 = 0.0f;
        #pragma unroll
        for (int k = 0; k < C_CLS / 4; ++k) {
            const float4 v = row4[k];
            const float m4 = fmaxf(fmaxf(v.x, v.y), fmaxf(v.z, v.w));
            const float mn = fmaxf(m, m4);
            s = s * __expf(m - mn) + __expf(v.x - mn) + __expf(v.y - mn)
              + __expf(v.z - mn) + __expf(v.w - mn);
            m = mn;
            if (k == C_CLS / 4 - 1) v79 = v.w;
        }
        const float lse = m + __logf(s);
        const float l_idx = pos ? cls_logits[(size_t)a * C_CLS + mlab] : v79;
        const float ce = lse - l_idx;
        const float p = __expf(-ce);
        const float om = 1.0f - p;
        const float fl = om * om * ce;
        const float af = (pos && mlab == 1) ? 0.25f : 0.75f;
        c_affl = af * fl;
        const float w = ab.z - ab.x, h = ab.w - ab.y;
        const float cx = ab.x + 0.5f * w, cy = ab.y + 0.5f * h;
        const float4 t = reinterpret_cast<const float4*>(bbox_reg)[a];
        const float pcx = cx + t.x * w, pcy = cy + t.y * h;
        const float pw = __expf(t.z * w) * w, ph = __expf(t.w * h) * h;
        const float p0 = pcx - 0.5f * pw, p1 = pcy - 0.5f * ph;
        const float p2 = pcx + 0.5f * pw, p3 = pcy + 0.5f * ph;
        const float lx2 = fmaxf(p0, mb.x), ly2 = fmaxf(p1, mb.y);
        const float rx2 = fminf(p2, mb.z), ry2 = fminf(p3, mb.w);
        const float iw2 = fmaxf(rx2 - lx2, 0.0f), ih2 = fmaxf(ry2 - ly2, 0.0f);
        const float inter2 = iw2 * ih2;
        const float area_p = (p2 - p0) * (p3 - p1);
        const float area_m = (mb.z - mb.x) * (mb.w - mb.y);
        const float uni = area_p + area_m - inter2;
        const float iou2 = inter2 * frcp(uni);
        const float elx = fminf(p0, mb.x), ely = fminf(p1, mb.y);
        const float erx = fmaxf(p2, mb.z), ery = fmaxf(p3, mb.w);
        const float ew = fmaxf(erx - elx, 0.0f), eh = fmaxf(ery - ely, 0.0f);
        const float earea = ew * eh;
        const float giou = iou2 - (earea - uni) * frcp(earea);
        c_giou = posf * giou;
        const float lr0 = mb.x - ab.x, lr1 = mb.z - ab.z;
        const float tb0 = mb.y - ab.y, tb1 = mb.w - ab.w;
        const float lrmax = fmaxf(lr0, lr1), lrmin = fminf(lr0, lr1);
        const float tbmax = fmaxf(tb0, tb1), tbmin = fminf(tb0, tb1);
        const float r_lr = fmaxf(lrmin * frcp(lrmax == 0.0f ? 1.0f : lrmax), 0.0f);
        const float r_tb = fmaxf(tbmin * frcp(tbmax == 0.0f ? 1.0f : tbmax), 0.0f);
        const float ctr_t = sqrtf(fmaxf(r_lr * r_tb, 1e-12f));
        const float c = centerness[a];
        const float bce = fmaxf(c, 0.0f) + log1pf(__expf(-fabsf(c))) - c * ctr_t;
        c_bce = posf * bce;
        c_pos = posf;
    }
    __shared__ float red[4][BLOCK / 64];
    float vals[4] = { c_affl, c_pos, c_giou, c_bce };
    #pragma unroll
    for (int i = 0; i < 4; ++i) {
        float v = vals[i];
        #pragma unroll
        for (int off = 32; off > 0; off >>= 1) v += __shfl_down(v, off, 64);
        if ((tid & 63) == 0) red[i][tid >> 6] = v;
    }
    __syncthreads();
    if (tid < 4) {
        float v = 0.f;
        #pragma unroll
        for (int w = 0; w < BLOCK / 64; ++w) v += red[tid][w];
        atomicAdd(&sums[tid], v);
    }
}

__global__ void detloss_final(const float* __restrict__ sums,
                              float* __restrict__ out, int A)
{
    const float s_affl = sums[0];
    const float npos   = sums[1];
    const float sgiou  = sums[2];
    const float sbce   = sums[3];
    float cls = s_affl / (float)A;
    const float denom = fmaxf(npos, 1.0f);
    float reg = 1.0f - sgiou / denom;
    float ctr = sbce / denom;
    const float has = (npos > 0.0f) ? 1.0f : 0.0f;
    cls *= has; reg *= has; ctr *= has;
    out[0] = cls + reg + ctr;
    out[1] = cls;
    out[2] = reg;
    out[3] = ctr;
}

extern "C" void kernel_launch(void* const* d_in, const int* in_sizes, int n_in,
                              void* d_out, int out_size, void* d_ws, size_t ws_size,
                              hipStream_t stream) {
    const float* anchors    = (const float*)d_in[0];
    const float* cls_logits = (const float*)d_in[1];
    const float* bbox_reg   = (const float*)d_in[2];
    const float* centerness = (const float*)d_in[3];
    const float* gt_boxes   = (const float*)d_in[4];
    const int*   gt_labels  = (const int*)d_in[5];
    const int A = in_sizes[0] / 4;
    const int G = in_sizes[4] / 4;

    float* sums = (float*)d_ws;
    const int grid = (A + BLOCK - 1) / BLOCK;

    const size_t need = (size_t)(8 + NCELLS + (size_t)NCELLS * CAP * 4
                                 + (size_t)NCELLS * CAP) * 4;
    hipMemsetAsync(sums, 0, 4 * sizeof(float), stream);

    if (ws_size >= need && G <= 256) {
        int*    cnts  = (int*)d_ws + 8;
        float4* boxes = (float4*)((float*)d_ws + 8 + NCELLS);
        int*    labs  = (int*)((float*)d_ws + 8 + NCELLS + (size_t)NCELLS * CAP * 4);

        k_build<<<NCELLS, 256, 0, stream>>>((const float4*)gt_boxes, gt_labels,
                                            cnts, boxes, labs, G);
        k_main<<<grid, BLOCK, 0, stream>>>(anchors, cls_logits, bbox_reg,
                                           centerness, gt_boxes, gt_labels,
                                           cnts, boxes, labs, sums, A, G);
    } else {
        const int Gc = G > G_MAX ? G_MAX : G;
        detloss_fallback<<<grid, BLOCK, 0, stream>>>(anchors, cls_logits, bbox_reg,
                                                     centerness, gt_boxes, gt_labels,
                                                     sums, A, Gc);
    }
    detloss_final<<<1, 1, 0, stream>>>(sums, (float*)d_out, A);
}